// Round 5
// baseline (520.592 us; speedup 1.0000x reference)
//
#include <hip/hip_runtime.h>

typedef unsigned int uint;
typedef unsigned short ushort;
typedef __attribute__((ext_vector_type(8))) short bf16x8;
typedef __attribute__((ext_vector_type(4))) float f32x4;

#define N_NODES 100000
#define N_EDGES 1600000
#define NB_C 256
#define TILE_C ((N_EDGES + NB_C - 1) / NB_C)
#define NB_D ((N_NODES + 511) / 512)
#define MG_GRID ((N_NODES + 63) / 64)
#define AGGS_GRID 2048
#define AGGS_M (AGGS_GRID / 8)
constexpr float BN_EPS = 1e-5f;

__device__ __forceinline__ float bflo(uint w) { return __uint_as_float(w << 16); }
__device__ __forceinline__ float bfhi(uint w) { return __uint_as_float(w & 0xffff0000u); }
__device__ __forceinline__ ushort f2bf(float x) {
    uint u = __float_as_uint(x);
    uint r = (u + 0x7fffu + ((u >> 16) & 1u)) >> 16;
    return (ushort)r;
}
__device__ __forceinline__ uint pack2(float a, float b) {
    return (uint)f2bf(a) | ((uint)f2bf(b) << 16);
}

// ---------------- edge_index dtype detection (int32 vs int64) ----------------
__global__ void detect_kernel(const int* __restrict__ ep, int* __restrict__ flag)
{
    __shared__ int cnt;
    if (threadIdx.x == 0) cnt = 0;
    __syncthreads();
    int nz = 0;
    for (int k = threadIdx.x; k < 1024; k += blockDim.x)
        if (ep[2 * k + 1] != 0) nz++;
    atomicAdd(&cnt, nz);
    __syncthreads();
    if (threadIdx.x == 0) *flag = (cnt == 0) ? 1 : 0;
}

// ---------------- CSR build: atomic-free bucket sort ----------------
__global__ __launch_bounds__(256) void coarseA_kernel(const int* __restrict__ ep,
                                                      const int* __restrict__ flag,
                                                      uint* __restrict__ ch)
{
    __shared__ uint lh[256];
    int t = threadIdx.x, blk = blockIdx.x;
    lh[t] = 0;
    __syncthreads();
    bool i64 = (*flag != 0);
    int start = blk * TILE_C;
    int end = start + TILE_C;
    if (end > N_EDGES) end = N_EDGES;
    for (int e = start + t; e < end; e += 256) {
        int d = i64 ? ep[2 * (N_EDGES + e)] : ep[N_EDGES + e];
        atomicAdd(&lh[d >> 9], 1u);
    }
    __syncthreads();
    ch[t * NB_C + blk] = lh[t];
}

__global__ void scanB_kernel(uint* __restrict__ ch, uint* __restrict__ bucketBase)
{
    __shared__ uint tot[256];
    int t = threadIdx.x;
    uint s = 0;
    for (int i = 0; i < NB_C; i++) s += ch[t * NB_C + i];
    tot[t] = s;
    __syncthreads();
    for (int off = 1; off < 256; off <<= 1) {
        uint add = (t >= off) ? tot[t - off] : 0u;
        __syncthreads();
        tot[t] += add;
        __syncthreads();
    }
    uint base = tot[t] - s;
    bucketBase[t] = base;
    if (t == 255) bucketBase[256] = base + s;
    uint run = base;
    for (int i = 0; i < NB_C; i++) {
        uint c = ch[t * NB_C + i];
        ch[t * NB_C + i] = run;
        run += c;
    }
}

__global__ __launch_bounds__(256) void scatterC_kernel(const int* __restrict__ ep,
                                                       const int* __restrict__ flag,
                                                       const uint* __restrict__ ch,
                                                       int2* __restrict__ pair)
{
    __shared__ uint loff[256];
    int t = threadIdx.x, blk = blockIdx.x;
    loff[t] = ch[t * NB_C + blk];
    __syncthreads();
    bool i64 = (*flag != 0);
    int start = blk * TILE_C;
    int end = start + TILE_C;
    if (end > N_EDGES) end = N_EDGES;
    for (int e = start + t; e < end; e += 256) {
        int s, d;
        if (i64) { s = ep[2 * e]; d = ep[2 * (N_EDGES + e)]; }
        else     { s = ep[e];     d = ep[N_EDGES + e]; }
        uint pos = atomicAdd(&loff[d >> 9], 1u);
        pair[pos] = make_int2(s, d);
    }
}

__global__ __launch_bounds__(256) void bucketD_kernel(const int2* __restrict__ pair,
                                                      const uint* __restrict__ bucketBase,
                                                      int* __restrict__ rowptr,
                                                      float* __restrict__ dinv,
                                                      int* __restrict__ colidx)
{
    __shared__ uint cnt[512], offp[512], s2[256];
    int bin = blockIdx.x, t = threadIdx.x;
    cnt[t] = 0; cnt[t + 256] = 0;
    __syncthreads();
    uint lo = bucketBase[bin], hi = bucketBase[bin + 1];
    for (uint p = lo + t; p < hi; p += 256)
        atomicAdd(&cnt[pair[p].y & 511], 1u);
    __syncthreads();
    uint a = cnt[2 * t], b = cnt[2 * t + 1];
    s2[t] = a + b;
    __syncthreads();
    for (int off = 1; off < 256; off <<= 1) {
        uint add = (t >= off) ? s2[t - off] : 0u;
        __syncthreads();
        s2[t] += add;
        __syncthreads();
    }
    uint excl = s2[t] - (a + b);
    offp[2 * t] = excl;
    offp[2 * t + 1] = excl + a;
    __syncthreads();
    for (int k = t; k < 512; k += 256) {
        int d = bin * 512 + k;
        if (d < N_NODES) {
            rowptr[d] = (int)(lo + offp[k]);
            dinv[d] = rsqrtf((float)(cnt[k] + 1));
        }
    }
    if (bin == 0 && t == 0) rowptr[N_NODES] = N_EDGES;
    __syncthreads();
    for (uint p = lo + t; p < hi; p += 256) {
        int2 pr = pair[p];
        uint pos = lo + atomicAdd(&offp[pr.y & 511], 1u);
        colidx[pos] = pr.x;
    }
}

// ---------------- xs sliced: [3][N][8]u, dims 2u,2u+1 = dinv*x (pad >=39 zero) ----------------
__global__ __launch_bounds__(256) void xscale_kernel(const float* __restrict__ x,
                                                     const float* __restrict__ dinv,
                                                     uint* __restrict__ xs)
{
    int idx = blockIdx.x * 256 + threadIdx.x;
    if (idx >= N_NODES * 24) return;
    int i = idx / 24;
    int u = idx - i * 24;
    int s = u >> 3, d = u & 7;
    int c0 = 2 * u, c1 = 2 * u + 1;
    float di = dinv[i];
    float v0 = (c0 < 39) ? x[i * 39 + c0] * di : 0.f;
    float v1 = (c1 < 39) ? x[i * 39 + c1] * di : 0.f;
    xs[((size_t)s * N_NODES + i) * 8 + d] = pack2(v0, v1);
}

// ---------------- W fragment packing ----------------
__global__ void packW_kernel(const float* __restrict__ W, ushort* __restrict__ out,
                             int din, int dout, int K)
{
    int CT = dout >> 4;
    int tot = (K >> 5) * CT * 64 * 8;
    for (int idx = blockIdx.x * 256 + threadIdx.x; idx < tot; idx += gridDim.x * 256) {
        int j = idx & 7;
        int lane = (idx >> 3) & 63;
        int slot = idx >> 9;
        int ct = slot % CT, kt = slot / CT;
        int k = kt * 32 + (lane >> 4) * 8 + j;
        int c = ct * 16 + (lane & 15);
        float v = (k < din) ? W[k * dout + c] : 0.f;
        out[idx] = f2bf(v);
    }
}

// ---------------- rowsumP: dinv gather (tiny table, no pinning needed) ----------------
__global__ __launch_bounds__(256) void rowsum_kernel(
    const int* __restrict__ rowptr, const int* __restrict__ colidx,
    const float* __restrict__ dinv, float* __restrict__ rowsumP)
{
    int tid = threadIdx.x;
    int lane = tid & 63, wid = tid >> 6;
    int g16 = lane >> 4, gl = lane & 15;
    int gid = (blockIdx.x * 4 + wid) * 4 + g16;
    int ng = gridDim.x * 16;
    for (int i0 = gid; i0 < N_NODES; i0 += ng) {
        int s0 = rowptr[i0], e0 = rowptr[i0 + 1];
        float ad = 0.f;
        for (int e = s0 + gl; e < e0; e += 16) ad += dinv[colidx[e]];
        ad += __shfl_xor(ad, 1); ad += __shfl_xor(ad, 2);
        ad += __shfl_xor(ad, 4); ad += __shfl_xor(ad, 8);
        if (gl == 0) {
            float di = dinv[i0];
            rowsumP[i0] = di * (ad + di);
        }
    }
}

// ---------------- sliced aggregation, XCD-pinned, one wave per node ----------------
// table: [SLICES][N][8]u (16 bf16 dims per slice).
// lane = d (0..7, dim pair) + 8*p (0..7, edge partition) -> 8-edge ILP, no divergence.
// MODE 0: out bf16 sliced = dinv_i * acc
// MODE 1: out bf16 sliced = relu(dinv_i*acc + bias), stats partials
// MODE 2: out f32 sliced  = relu(dinv_i*acc + bias), stats partials
template <int SLICES, int MODE>
__global__ __launch_bounds__(256) void aggs_kernel(
    const uint* __restrict__ table, const int* __restrict__ rowptr,
    const int* __restrict__ colidx, const float* __restrict__ dinv,
    const float* __restrict__ bias,
    uint* __restrict__ outU, float* __restrict__ outF,
    float* __restrict__ Psum, float* __restrict__ Psq)
{
    int bid = blockIdx.x;
    int xcd = bid & 7;
    int M = gridDim.x >> 3;
    int slice, sub, ns;
    if constexpr (SLICES == 4) { slice = xcd >> 1; sub = xcd & 1; ns = 2; }
    else if constexpr (SLICES == 2) { slice = xcd >> 2; sub = xcd & 3; ns = 4; }
    else {
        if (xcd < 3) { slice = 0; sub = xcd; ns = 3; }
        else if (xcd < 6) { slice = 1; sub = xcd - 3; ns = 3; }
        else { slice = 2; sub = xcd - 6; ns = 2; }
    }
    int v = (bid >> 3) * ns + sub;  // block index within this slice
    int V = M * ns;                 // blocks serving this slice

    int tid = threadIdx.x;
    int lane = tid & 63, wid = tid >> 6;
    int d = lane & 7, p = lane >> 3;
    const uint* base = table + (size_t)slice * N_NODES * 8;

    float bx = 0.f, by = 0.f;
    if constexpr (MODE >= 1) {
        bx = bias[slice * 16 + 2 * d];
        by = bias[slice * 16 + 2 * d + 1];
    }
    float lsx = 0.f, lsy = 0.f, lqx = 0.f, lqy = 0.f;

    for (int i = v * 4 + wid; i < N_NODES; i += V * 4) {
        int iu = __builtin_amdgcn_readfirstlane(i);
        int s0 = rowptr[iu], e0 = rowptr[iu + 1];
        float ax = 0.f, ay = 0.f;
        if (p == 0) {
            uint w = base[((size_t)iu << 3) + d];
            ax = bflo(w); ay = bfhi(w);
        }
        int e = s0 + p;
        for (; e + 8 < e0; e += 16) {
            int j0 = colidx[e], j1 = colidx[e + 8];
            uint w0 = base[((size_t)j0 << 3) + d];
            uint w1 = base[((size_t)j1 << 3) + d];
            ax += bflo(w0); ay += bfhi(w0);
            ax += bflo(w1); ay += bfhi(w1);
        }
        if (e < e0) {
            uint w = base[((size_t)colidx[e] << 3) + d];
            ax += bflo(w); ay += bfhi(w);
        }
        ax += __shfl_xor(ax, 8); ax += __shfl_xor(ax, 16); ax += __shfl_xor(ax, 32);
        ay += __shfl_xor(ay, 8); ay += __shfl_xor(ay, 16); ay += __shfl_xor(ay, 32);
        if (p == 0) {
            float di = dinv[iu];
            if constexpr (MODE == 0) {
                outU[((size_t)slice * N_NODES + iu) * 8 + d] = pack2(di * ax, di * ay);
            } else {
                float tx = fmaxf(fmaf(di, ax, bx), 0.f);
                float ty = fmaxf(fmaf(di, ay, by), 0.f);
                if constexpr (MODE == 1)
                    outU[((size_t)slice * N_NODES + iu) * 8 + d] = pack2(tx, ty);
                else
                    *(float2*)&outF[((size_t)slice * N_NODES + iu) * 16 + 2 * d] =
                        make_float2(tx, ty);
                lsx += tx; lsy += ty;
                lqx += tx * tx; lqy += ty * ty;
            }
        }
    }

    if constexpr (MODE >= 1) {
        __shared__ float ssum[16], ssq[16];
        if (tid < 16) { ssum[tid] = 0.f; ssq[tid] = 0.f; }
        __syncthreads();
        if (p == 0) {
            atomicAdd(&ssum[2 * d], lsx); atomicAdd(&ssum[2 * d + 1], lsy);
            atomicAdd(&ssq[2 * d], lqx);  atomicAdd(&ssq[2 * d + 1], lqy);
        }
        __syncthreads();
        if (tid < 16) {
            Psum[(size_t)(slice * 16 + tid) * V + v] = ssum[tid];
            Psq[(size_t)(slice * 16 + tid) * V + v] = ssq[tid];
        }
    }
}

// ---------------- MFMA GEMM ----------------
// MODE 0: t=relu(acc+bias); stats; out bf16 = dinv[r]*t
// MODE 1: t=relu(acc+bias+rowsumP[r]*bias2); stats; out bf16 = t (row-major)
// MODE 2: z=acc+bias; out bf16 = dinv[r]*z
// ASLICED: A stored [K/16][N][16] bf16; OSLICED: out stored [DOUT/16][N][16] bf16
template <int K, int DOUT, int MODE, int ASLICED, int OSLICED>
__global__ __launch_bounds__(256) void mgemm_kernel(
    const ushort* __restrict__ A, const ushort* __restrict__ Wfrag,
    const float* __restrict__ bias, const float* __restrict__ bias2,
    const float* __restrict__ rowsumP, const float* __restrict__ dinv,
    ushort* __restrict__ outB, float* __restrict__ Psum, float* __restrict__ Psq)
{
    constexpr int KT = K / 32, CT = DOUT / 16;
    int tid = threadIdx.x;
    int lane = tid & 63, wid = tid >> 6;
    int r0 = blockIdx.x * 64 + wid * 16;
    int arow = r0 + (lane & 15);
    if (arow >= N_NODES) arow = N_NODES - 1;

    f32x4 acc[CT];
#pragma unroll
    for (int ct = 0; ct < CT; ct++) acc[ct] = (f32x4){0.f, 0.f, 0.f, 0.f};

#pragma unroll
    for (int kt = 0; kt < KT; kt++) {
        int k0 = kt * 32 + (lane >> 4) * 8;
        const ushort* ap;
        if constexpr (ASLICED)
            ap = A + (((size_t)(k0 >> 4) * N_NODES + arow) << 4) + (k0 & 15);
        else
            ap = A + (size_t)arow * K + k0;
        bf16x8 af = *(const bf16x8*)ap;
        const ushort* wp = Wfrag + ((size_t)(kt * CT) * 64 + lane) * 8;
#pragma unroll
        for (int ct = 0; ct < CT; ct++) {
            bf16x8 bfr = *(const bf16x8*)(wp + (size_t)ct * 64 * 8);
            acc[ct] = __builtin_amdgcn_mfma_f32_16x16x32_bf16(af, bfr, acc[ct], 0, 0, 0);
        }
    }

    int colbase = lane & 15;
    int rgrp = lane >> 4;
    int rows[4]; bool rok[4];
    float rP[4], rD[4];
#pragma unroll
    for (int i = 0; i < 4; i++) {
        int r = r0 + rgrp * 4 + i;
        rows[i] = r;
        rok[i] = (r < N_NODES);
        int rc = rok[i] ? r : 0;
        if constexpr (MODE == 1) rP[i] = rowsumP[rc];
        else rD[i] = dinv[rc];
    }

    __shared__ float ssum[DOUT], ssq[DOUT];
    if constexpr (MODE <= 1) {
        for (int c = tid; c < DOUT; c += 256) { ssum[c] = 0.f; ssq[c] = 0.f; }
        __syncthreads();
    }

#pragma unroll
    for (int ct = 0; ct < CT; ct++) {
        int col = ct * 16 + colbase;
        float b = bias[col];
        float b2 = 0.f;
        if constexpr (MODE == 1) b2 = bias2[col];
        float cs = 0.f, cq = 0.f;
#pragma unroll
        for (int i = 0; i < 4; i++) {
            float v = acc[ct][i] + b;
            if constexpr (MODE == 1) v = fmaf(rP[i], b2, v);
            if constexpr (MODE <= 1) v = fmaxf(v, 0.f);
            float w = (MODE == 1) ? v : rD[i] * v;
            if (rok[i]) {
                size_t addr;
                if constexpr (OSLICED)
                    addr = ((size_t)ct * N_NODES + rows[i]) * 16 + colbase;
                else
                    addr = (size_t)rows[i] * DOUT + col;
                outB[addr] = f2bf(w);
                if constexpr (MODE <= 1) { cs += v; cq += v * v; }
            }
        }
        if constexpr (MODE <= 1) {
            cs += __shfl_xor(cs, 16); cs += __shfl_xor(cs, 32);
            cq += __shfl_xor(cq, 16); cq += __shfl_xor(cq, 32);
            if (rgrp == 0) {
                atomicAdd(&ssum[col], cs);
                atomicAdd(&ssq[col], cq);
            }
        }
    }
    if constexpr (MODE <= 1) {
        __syncthreads();
        for (int c = tid; c < DOUT; c += 256) {
            Psum[(size_t)c * gridDim.x + blockIdx.x] = ssum[c];
            Psq[(size_t)c * gridDim.x + blockIdx.x] = ssq[c];
        }
    }
}

// ---------------- BN stat reduce -> scale/shift ----------------
__global__ __launch_bounds__(256) void reduce_bn_kernel(
    const float* __restrict__ Psum, const float* __restrict__ Psq, int nb,
    const float* __restrict__ g, const float* __restrict__ be,
    float* __restrict__ sOut, float* __restrict__ uOut)
{
    int c = blockIdx.x, t = threadIdx.x;
    float s = 0.f, q = 0.f;
    for (int i = t; i < nb; i += 256) {
        s += Psum[(size_t)c * nb + i];
        q += Psq[(size_t)c * nb + i];
    }
    __shared__ float rs[256], rq[256];
    rs[t] = s; rq[t] = q;
    __syncthreads();
    for (int off = 128; off > 0; off >>= 1) {
        if (t < off) { rs[t] += rs[t + off]; rq[t] += rq[t + off]; }
        __syncthreads();
    }
    if (t == 0) {
        float mu = rs[0] * (1.0f / N_NODES);
        float var = rq[0] * (1.0f / N_NODES) - mu * mu;
        float sv = g[c] * rsqrtf(var + BN_EPS);
        sOut[c] = sv;
        uOut[c] = be[c] - mu * sv;
    }
}

// ---------------- fold: Wf = s (row) * W ; v[c] = u @ W[:,c] ----------------
__global__ void foldW_kernel(const float* __restrict__ W, const float* __restrict__ s,
                             const float* __restrict__ u, float* __restrict__ Wf,
                             float* __restrict__ v, int din, int dout)
{
    int c = blockIdx.x, t = threadIdx.x;
    float contrib = 0.f;
    if (t < din) {
        float w = W[t * dout + c];
        Wf[t * dout + c] = s[t] * w;
        contrib = u[t] * w;
    }
    __shared__ float red[128];
    red[t] = contrib;
    __syncthreads();
    for (int off = 64; off > 0; off >>= 1) {
        if (t < off) red[t] += red[t + off];
        __syncthreads();
    }
    if (t == 0) v[c] = red[0];
}

// ---------------- final: h4 = s4*t4+u4 (t4 sliced [2][N][16]f), logits = h4@Wc+bc ----------------
__global__ __launch_bounds__(256) void final_kernel(
    const float* __restrict__ t4, const float* __restrict__ sArr,
    const float* __restrict__ uArr, const float* __restrict__ Wc,
    const float* __restrict__ bc, float* __restrict__ out_logits,
    float* __restrict__ out_h)
{
    __shared__ float sc[32], sh2[32], Wcs[160], bcs[5];
    int t = threadIdx.x;
    if (t < 32) { sc[t] = sArr[t]; sh2[t] = uArr[t]; }
    if (t < 160) Wcs[t] = Wc[t];
    if (t < 5) bcs[t] = bc[t];
    __syncthreads();
    int i = blockIdx.x * blockDim.x + t;
    if (i >= N_NODES) return;
    float hv[32];
#pragma unroll
    for (int f0 = 0; f0 < 16; f0 += 4) {
        float4 v = *(const float4*)&t4[(size_t)i * 16 + f0];
        hv[f0 + 0] = fmaf(sc[f0 + 0], v.x, sh2[f0 + 0]);
        hv[f0 + 1] = fmaf(sc[f0 + 1], v.y, sh2[f0 + 1]);
        hv[f0 + 2] = fmaf(sc[f0 + 2], v.z, sh2[f0 + 2]);
        hv[f0 + 3] = fmaf(sc[f0 + 3], v.w, sh2[f0 + 3]);
    }
#pragma unroll
    for (int f0 = 0; f0 < 16; f0 += 4) {
        float4 v = *(const float4*)&t4[((size_t)N_NODES + i) * 16 + f0];
        hv[16 + f0 + 0] = fmaf(sc[16 + f0 + 0], v.x, sh2[16 + f0 + 0]);
        hv[16 + f0 + 1] = fmaf(sc[16 + f0 + 1], v.y, sh2[16 + f0 + 1]);
        hv[16 + f0 + 2] = fmaf(sc[16 + f0 + 2], v.z, sh2[16 + f0 + 2]);
        hv[16 + f0 + 3] = fmaf(sc[16 + f0 + 3], v.w, sh2[16 + f0 + 3]);
    }
#pragma unroll
    for (int f0 = 0; f0 < 32; f0 += 4) {
        float4 v = {hv[f0], hv[f0 + 1], hv[f0 + 2], hv[f0 + 3]};
        *(float4*)&out_h[(size_t)i * 32 + f0] = v;
    }
    float o[5];
#pragma unroll
    for (int c = 0; c < 5; c++) o[c] = bcs[c];
#pragma unroll
    for (int f = 0; f < 32; f++) {
        float hvf = hv[f];
#pragma unroll
        for (int c = 0; c < 5; c++) o[c] = fmaf(hvf, Wcs[f * 5 + c], o[c]);
    }
#pragma unroll
    for (int c = 0; c < 5; c++) out_logits[(size_t)i * 5 + c] = o[c];
}

extern "C" void kernel_launch(void* const* d_in, const int* in_sizes, int n_in,
                              void* d_out, int out_size, void* d_ws, size_t ws_size,
                              hipStream_t stream)
{
    const float* x = (const float*)d_in[0];
    const int* ei = (const int*)d_in[1];
    const float* W1 = (const float*)d_in[2];
    const float* b1 = (const float*)d_in[3];
    const float* g1 = (const float*)d_in[4];
    const float* be1 = (const float*)d_in[5];
    const float* W2 = (const float*)d_in[6];
    const float* b2 = (const float*)d_in[7];
    const float* g2 = (const float*)d_in[8];
    const float* be2 = (const float*)d_in[9];
    const float* W3 = (const float*)d_in[10];
    const float* b3 = (const float*)d_in[11];
    const float* g3 = (const float*)d_in[12];
    const float* be3 = (const float*)d_in[13];
    const float* W4 = (const float*)d_in[14];
    const float* b4 = (const float*)d_in[15];
    const float* g4 = (const float*)d_in[16];
    const float* be4 = (const float*)d_in[17];
    const float* Wc = (const float*)d_in[18];
    const float* bc = (const float*)d_in[19];

    char* ws = (char*)d_ws;
    size_t off = 0;
    auto alloc = [&](size_t bytes) -> void* {
        void* p = ws + off;
        off += (bytes + 255) & ~(size_t)255;
        return p;
    };
    uint* ch = (uint*)alloc(65536 * 4);
    uint* bucketBase = (uint*)alloc(257 * 4);
    int2* pair = (int2*)alloc((size_t)N_EDGES * 8);
    int* rowptr = (int*)alloc((size_t)(N_NODES + 1) * 4);
    float* dinv = (float*)alloc((size_t)N_NODES * 4);
    int* colidx = (int*)alloc((size_t)N_EDGES * 4);
    int* flag = (int*)alloc(256);
    float* rowsumP = (float*)alloc((size_t)N_NODES * 4);
    uint* xs = (uint*)alloc((size_t)N_NODES * 24 * 4);   // [3][N][8]u
    float* Wf = (float*)alloc(128 * 128 * 4);
    ushort* Wfrag = (ushort*)alloc(32768);
    float* vB = (float*)alloc(128 * 4);
    float* sArr = (float*)alloc(128 * 4);
    float* uArr = (float*)alloc(128 * 4);
    float* Psum = (float*)alloc((size_t)128 * 2048 * 4);
    float* Psq = (float*)alloc((size_t)128 * 2048 * 4);
    uint* P = (uint*)alloc((size_t)N_NODES * 32 * 4);    // sliced [4][N][8]u: a1 -> a2 -> z3s -> z4s
    uint* Q = (uint*)alloc((size_t)N_NODES * 32 * 4);    // sliced [4][N][8]u: t1s -> t3
    uint* R = (uint*)alloc((size_t)N_NODES * 64 * 4);    // t2 [N,128]bf16 row-major, then t4 [2][N][16]f32
    if (off > ws_size) return;

    constexpr int V4 = AGGS_M * 2;  // blocks per slice, SLICES=4
    constexpr int V2 = AGGS_M * 4;  // blocks per slice, SLICES=2

    // ---- CSR build ----
    detect_kernel<<<1, 256, 0, stream>>>(ei, flag);
    coarseA_kernel<<<NB_C, 256, 0, stream>>>(ei, flag, ch);
    scanB_kernel<<<1, 256, 0, stream>>>(ch, bucketBase);
    scatterC_kernel<<<NB_C, 256, 0, stream>>>(ei, flag, ch, pair);
    bucketD_kernel<<<NB_D, 256, 0, stream>>>(pair, bucketBase, rowptr, dinv, colidx);

    // ---- prep ----
    xscale_kernel<<<(N_NODES * 24 + 255) / 256, 256, 0, stream>>>(x, dinv, xs);
    packW_kernel<<<16, 256, 0, stream>>>(W1, Wfrag, 39, 64, 64);
    rowsum_kernel<<<512, 256, 0, stream>>>(rowptr, colidx, dinv, rowsumP);
    hipMemsetAsync(P + (size_t)3 * N_NODES * 8, 0, (size_t)N_NODES * 32, stream); // a1 slice3 = 0

    // ---- Layer 1 ----
    aggs_kernel<3, 0><<<AGGS_GRID, 256, 0, stream>>>(xs, rowptr, colidx, dinv, nullptr,
                                                     P, nullptr, nullptr, nullptr);
    mgemm_kernel<64, 64, 0, 1, 1><<<MG_GRID, 256, 0, stream>>>(
        (const ushort*)P, Wfrag, b1, nullptr, nullptr, dinv, (ushort*)Q, Psum, Psq);
    reduce_bn_kernel<<<64, 256, 0, stream>>>(Psum, Psq, MG_GRID, g1, be1, sArr, uArr);
    foldW_kernel<<<128, 128, 0, stream>>>(W2, sArr, uArr, Wf, vB, 64, 128);
    packW_kernel<<<32, 256, 0, stream>>>(Wf, Wfrag, 64, 128, 64);

    // ---- Layer 2 ----
    aggs_kernel<4, 0><<<AGGS_GRID, 256, 0, stream>>>(Q, rowptr, colidx, dinv, nullptr,
                                                     P, nullptr, nullptr, nullptr);
    mgemm_kernel<64, 128, 1, 1, 0><<<MG_GRID, 256, 0, stream>>>(
        (const ushort*)P, Wfrag, b2, vB, rowsumP, nullptr, (ushort*)R, Psum, Psq);
    reduce_bn_kernel<<<128, 256, 0, stream>>>(Psum, Psq, MG_GRID, g2, be2, sArr, uArr);
    foldW_kernel<<<64, 128, 0, stream>>>(W3, sArr, uArr, Wf, vB, 128, 64);
    packW_kernel<<<32, 256, 0, stream>>>(Wf, Wfrag, 128, 64, 128);

    // ---- Layer 3 ----
    mgemm_kernel<128, 64, 2, 0, 1><<<MG_GRID, 256, 0, stream>>>(
        (const ushort*)R, Wfrag, vB, nullptr, nullptr, dinv, (ushort*)P, nullptr, nullptr);
    aggs_kernel<4, 1><<<AGGS_GRID, 256, 0, stream>>>(P, rowptr, colidx, dinv, b3,
                                                     Q, nullptr, Psum, Psq);
    reduce_bn_kernel<<<64, 256, 0, stream>>>(Psum, Psq, V4, g3, be3, sArr, uArr);
    foldW_kernel<<<32, 128, 0, stream>>>(W4, sArr, uArr, Wf, vB, 64, 32);
    packW_kernel<<<16, 256, 0, stream>>>(Wf, Wfrag, 64, 32, 64);

    // ---- Layer 4 ----
    mgemm_kernel<64, 32, 2, 1, 1><<<MG_GRID, 256, 0, stream>>>(
        (const ushort*)Q, Wfrag, vB, nullptr, nullptr, dinv, (ushort*)P, nullptr, nullptr);
    aggs_kernel<2, 2><<<AGGS_GRID, 256, 0, stream>>>(P, rowptr, colidx, dinv, b4,
                                                     nullptr, (float*)R, Psum, Psq);
    reduce_bn_kernel<<<32, 256, 0, stream>>>(Psum, Psq, V2, g4, be4, sArr, uArr);

    // ---- final ----
    float* out_logits = (float*)d_out;
    float* out_h = (float*)d_out + (size_t)N_NODES * 5;
    final_kernel<<<(N_NODES + 255) / 256, 256, 0, stream>>>((const float*)R, sArr, uArr,
                                                            Wc, bc, out_logits, out_h);
}

// Round 6
// 388.679 us; speedup vs baseline: 1.3394x; 1.3394x over previous
//
#include <hip/hip_runtime.h>

typedef unsigned int uint;
typedef unsigned short ushort;
typedef __attribute__((ext_vector_type(8))) short bf16x8;
typedef __attribute__((ext_vector_type(4))) float f32x4;

#define N_NODES 100000
#define N_EDGES 1600000
#define NB_C 256
#define TILE_C ((N_EDGES + NB_C - 1) / NB_C)
#define NB_D ((N_NODES + 511) / 512)
#define MG_GRID ((N_NODES + 63) / 64)
#define AGG_GRID 2048
constexpr float BN_EPS = 1e-5f;

__device__ __forceinline__ float bflo(uint w) { return __uint_as_float(w << 16); }
__device__ __forceinline__ float bfhi(uint w) { return __uint_as_float(w & 0xffff0000u); }
__device__ __forceinline__ ushort f2bf(float x) {
    uint u = __float_as_uint(x);
    uint r = (u + 0x7fffu + ((u >> 16) & 1u)) >> 16;
    return (ushort)r;
}
__device__ __forceinline__ uint pack2(float a, float b) {
    return (uint)f2bf(a) | ((uint)f2bf(b) << 16);
}

// ---------------- edge_index dtype detection (int32 vs int64) ----------------
__global__ void detect_kernel(const int* __restrict__ ep, int* __restrict__ flag)
{
    __shared__ int cnt;
    if (threadIdx.x == 0) cnt = 0;
    __syncthreads();
    int nz = 0;
    for (int k = threadIdx.x; k < 1024; k += blockDim.x)
        if (ep[2 * k + 1] != 0) nz++;
    atomicAdd(&cnt, nz);
    __syncthreads();
    if (threadIdx.x == 0) *flag = (cnt == 0) ? 1 : 0;
}

// ---------------- CSR build: atomic-free bucket sort ----------------
__global__ __launch_bounds__(256) void coarseA_kernel(const int* __restrict__ ep,
                                                      const int* __restrict__ flag,
                                                      uint* __restrict__ ch)
{
    __shared__ uint lh[256];
    int t = threadIdx.x, blk = blockIdx.x;
    lh[t] = 0;
    __syncthreads();
    bool i64 = (*flag != 0);
    int start = blk * TILE_C;
    int end = start + TILE_C;
    if (end > N_EDGES) end = N_EDGES;
    for (int e = start + t; e < end; e += 256) {
        int d = i64 ? ep[2 * (N_EDGES + e)] : ep[N_EDGES + e];
        atomicAdd(&lh[d >> 9], 1u);
    }
    __syncthreads();
    ch[t * NB_C + blk] = lh[t];
}

__global__ void scanB_kernel(uint* __restrict__ ch, uint* __restrict__ bucketBase)
{
    __shared__ uint tot[256];
    int t = threadIdx.x;
    uint s = 0;
    for (int i = 0; i < NB_C; i++) s += ch[t * NB_C + i];
    tot[t] = s;
    __syncthreads();
    for (int off = 1; off < 256; off <<= 1) {
        uint add = (t >= off) ? tot[t - off] : 0u;
        __syncthreads();
        tot[t] += add;
        __syncthreads();
    }
    uint base = tot[t] - s;
    bucketBase[t] = base;
    if (t == 255) bucketBase[256] = base + s;
    uint run = base;
    for (int i = 0; i < NB_C; i++) {
        uint c = ch[t * NB_C + i];
        ch[t * NB_C + i] = run;
        run += c;
    }
}

__global__ __launch_bounds__(256) void scatterC_kernel(const int* __restrict__ ep,
                                                       const int* __restrict__ flag,
                                                       const uint* __restrict__ ch,
                                                       int2* __restrict__ pair)
{
    __shared__ uint loff[256];
    int t = threadIdx.x, blk = blockIdx.x;
    loff[t] = ch[t * NB_C + blk];
    __syncthreads();
    bool i64 = (*flag != 0);
    int start = blk * TILE_C;
    int end = start + TILE_C;
    if (end > N_EDGES) end = N_EDGES;
    for (int e = start + t; e < end; e += 256) {
        int s, d;
        if (i64) { s = ep[2 * e]; d = ep[2 * (N_EDGES + e)]; }
        else     { s = ep[e];     d = ep[N_EDGES + e]; }
        uint pos = atomicAdd(&loff[d >> 9], 1u);
        pair[pos] = make_int2(s, d);
    }
}

__global__ __launch_bounds__(256) void bucketD_kernel(const int2* __restrict__ pair,
                                                      const uint* __restrict__ bucketBase,
                                                      int* __restrict__ rowptr,
                                                      float* __restrict__ dinv,
                                                      int* __restrict__ colidx)
{
    __shared__ uint cnt[512], offp[512], s2[256];
    int bin = blockIdx.x, t = threadIdx.x;
    cnt[t] = 0; cnt[t + 256] = 0;
    __syncthreads();
    uint lo = bucketBase[bin], hi = bucketBase[bin + 1];
    for (uint p = lo + t; p < hi; p += 256)
        atomicAdd(&cnt[pair[p].y & 511], 1u);
    __syncthreads();
    uint a = cnt[2 * t], b = cnt[2 * t + 1];
    s2[t] = a + b;
    __syncthreads();
    for (int off = 1; off < 256; off <<= 1) {
        uint add = (t >= off) ? s2[t - off] : 0u;
        __syncthreads();
        s2[t] += add;
        __syncthreads();
    }
    uint excl = s2[t] - (a + b);
    offp[2 * t] = excl;
    offp[2 * t + 1] = excl + a;
    __syncthreads();
    for (int k = t; k < 512; k += 256) {
        int d = bin * 512 + k;
        if (d < N_NODES) {
            rowptr[d] = (int)(lo + offp[k]);
            dinv[d] = rsqrtf((float)(cnt[k] + 1));
        }
    }
    if (bin == 0 && t == 0) rowptr[N_NODES] = N_EDGES;
    __syncthreads();
    for (uint p = lo + t; p < hi; p += 256) {
        int2 pr = pair[p];
        uint pos = lo + atomicAdd(&offp[pr.y & 511], 1u);
        colidx[pos] = pr.x;
    }
}

// ---------------- xs[i][c] = bf16(dinv[i]*x[i][c]) padded to 64 cols ----------------
__global__ __launch_bounds__(256) void xscale_kernel(const float* __restrict__ x,
                                                     const float* __restrict__ dinv,
                                                     uint* __restrict__ xs)
{
    int idx = blockIdx.x * 256 + threadIdx.x;
    if (idx >= N_NODES * 32) return;
    int i = idx >> 5;
    int u = idx & 31;
    int c0 = 2 * u, c1 = 2 * u + 1;
    float di = dinv[i];
    float v0 = (c0 < 39) ? x[i * 39 + c0] * di : 0.f;
    float v1 = (c1 < 39) ? x[i * 39 + c1] * di : 0.f;
    xs[idx] = pack2(v0, v1);
}

// ---------------- W fragment packing ----------------
__global__ void packW_kernel(const float* __restrict__ W, ushort* __restrict__ out,
                             int din, int dout, int K)
{
    int CT = dout >> 4;
    int tot = (K >> 5) * CT * 64 * 8;
    for (int idx = blockIdx.x * 256 + threadIdx.x; idx < tot; idx += gridDim.x * 256) {
        int j = idx & 7;
        int lane = (idx >> 3) & 63;
        int slot = idx >> 9;
        int ct = slot % CT, kt = slot / CT;
        int k = kt * 32 + (lane >> 4) * 8 + j;
        int c = ct * 16 + (lane & 15);
        float v = (k < din) ? W[k * dout + c] : 0.f;
        out[idx] = f2bf(v);
    }
}

// ---------------- rowsumP: dinv gather (tiny table) ----------------
__global__ __launch_bounds__(256) void rowsum_kernel(
    const int* __restrict__ rowptr, const int* __restrict__ colidx,
    const float* __restrict__ dinv, float* __restrict__ rowsumP)
{
    int tid = threadIdx.x;
    int lane = tid & 63, wid = tid >> 6;
    int g16 = lane >> 4, gl = lane & 15;
    int gid = (blockIdx.x * 4 + wid) * 4 + g16;
    int ng = gridDim.x * 16;
    for (int i0 = gid; i0 < N_NODES; i0 += ng) {
        int s0 = rowptr[i0], e0 = rowptr[i0 + 1];
        float ad = 0.f;
        for (int e = s0 + gl; e < e0; e += 16) ad += dinv[colidx[e]];
        ad += __shfl_xor(ad, 1); ad += __shfl_xor(ad, 2);
        ad += __shfl_xor(ad, 4); ad += __shfl_xor(ad, 8);
        if (gl == 0) {
            float di = dinv[i0];
            rowsumP[i0] = di * (ad + di);
        }
    }
}

// ---------------- aggregation: wide dwordx4 gathers, one wave per node ----------------
// table: row-major [N][D] bf16 (dinv_j-prescaled). lane = seg(D/8 x 16B) x slot(edges).
// MODE 0: out bf16 = dinv_i * acc
// MODE 1: out bf16 = relu(dinv_i*acc + bias), stats partials
// MODE 2: out f32  = relu(dinv_i*acc + bias), stats partials
template <int D, int MODE>
__global__ __launch_bounds__(256) void agg_kernel(
    const ushort* __restrict__ table, const int* __restrict__ rowptr,
    const int* __restrict__ colidx, const float* __restrict__ dinv,
    const float* __restrict__ bias,
    ushort* __restrict__ outB, float* __restrict__ outF,
    float* __restrict__ Psum, float* __restrict__ Psq)
{
    constexpr int LPE = D / 8;   // lanes per edge (16B chunks per row)
    constexpr int S = 64 / LPE;  // edge slots per wave
    int tid = threadIdx.x;
    int lane = tid & 63, wid = tid >> 6;
    int seg = lane & (LPE - 1);
    int slot = lane / LPE;
    const ushort* segbase = table + seg * 8;

    float bv[8];
    if constexpr (MODE >= 1) {
        float4 b0 = *(const float4*)&bias[seg * 8];
        float4 b1 = *(const float4*)&bias[seg * 8 + 4];
        bv[0] = b0.x; bv[1] = b0.y; bv[2] = b0.z; bv[3] = b0.w;
        bv[4] = b1.x; bv[5] = b1.y; bv[6] = b1.z; bv[7] = b1.w;
    }
    float lsum[8] = {}, lsq[8] = {};

    for (int i = blockIdx.x * 4 + wid; i < N_NODES; i += gridDim.x * 4) {
        int iu = __builtin_amdgcn_readfirstlane(i);
        int s0 = rowptr[iu], e0 = rowptr[iu + 1];
        float acc[8] = {};
        if (slot == 0) {
            const uint4 w = *(const uint4*)(segbase + (size_t)iu * D);
            acc[0] = bflo(w.x); acc[1] = bfhi(w.x);
            acc[2] = bflo(w.y); acc[3] = bfhi(w.y);
            acc[4] = bflo(w.z); acc[5] = bfhi(w.z);
            acc[6] = bflo(w.w); acc[7] = bfhi(w.w);
        }
        for (int eb = s0; eb < e0; eb += S) {
            int e = eb + slot;
            if (e < e0) {
                int j = colidx[e];
                const uint4 w = *(const uint4*)(segbase + (size_t)j * D);
                acc[0] += bflo(w.x); acc[1] += bfhi(w.x);
                acc[2] += bflo(w.y); acc[3] += bfhi(w.y);
                acc[4] += bflo(w.z); acc[5] += bfhi(w.z);
                acc[6] += bflo(w.w); acc[7] += bfhi(w.w);
            }
        }
#pragma unroll
        for (int m = LPE; m < 64; m <<= 1) {
#pragma unroll
            for (int v = 0; v < 8; v++) acc[v] += __shfl_xor(acc[v], m);
        }
        if (slot == 0) {
            float di = dinv[iu];
            if constexpr (MODE == 0) {
                uint4 pk;
                pk.x = pack2(di * acc[0], di * acc[1]);
                pk.y = pack2(di * acc[2], di * acc[3]);
                pk.z = pack2(di * acc[4], di * acc[5]);
                pk.w = pack2(di * acc[6], di * acc[7]);
                *(uint4*)(outB + (size_t)iu * D + seg * 8) = pk;
            } else {
                float t[8];
#pragma unroll
                for (int v = 0; v < 8; v++) {
                    t[v] = fmaxf(fmaf(di, acc[v], bv[v]), 0.f);
                    lsum[v] += t[v];
                    lsq[v] += t[v] * t[v];
                }
                if constexpr (MODE == 1) {
                    uint4 pk;
                    pk.x = pack2(t[0], t[1]); pk.y = pack2(t[2], t[3]);
                    pk.z = pack2(t[4], t[5]); pk.w = pack2(t[6], t[7]);
                    *(uint4*)(outB + (size_t)iu * D + seg * 8) = pk;
                } else {
                    float4 f0 = {t[0], t[1], t[2], t[3]};
                    float4 f1 = {t[4], t[5], t[6], t[7]};
                    *(float4*)(outF + (size_t)iu * D + seg * 8) = f0;
                    *(float4*)(outF + (size_t)iu * D + seg * 8 + 4) = f1;
                }
            }
        }
    }

    if constexpr (MODE >= 1) {
        __shared__ float ssum[D], ssq[D];
        for (int c = tid; c < D; c += 256) { ssum[c] = 0.f; ssq[c] = 0.f; }
        __syncthreads();
        if (slot == 0) {
#pragma unroll
            for (int v = 0; v < 8; v++) {
                atomicAdd(&ssum[seg * 8 + v], lsum[v]);
                atomicAdd(&ssq[seg * 8 + v], lsq[v]);
            }
        }
        __syncthreads();
        for (int c = tid; c < D; c += 256) {
            Psum[(size_t)c * gridDim.x + blockIdx.x] = ssum[c];
            Psq[(size_t)c * gridDim.x + blockIdx.x] = ssq[c];
        }
    }
}

// ---------------- MFMA GEMM (row-major A and out) ----------------
// MODE 0: t=relu(acc+bias); stats; out bf16 = dinv[r]*t
// MODE 1: t=relu(acc+bias+rowsumP[r]*bias2); stats; out bf16 = t
// MODE 2: z=acc+bias; out bf16 = dinv[r]*z
template <int K, int DOUT, int MODE>
__global__ __launch_bounds__(256) void mgemm_kernel(
    const ushort* __restrict__ A, const ushort* __restrict__ Wfrag,
    const float* __restrict__ bias, const float* __restrict__ bias2,
    const float* __restrict__ rowsumP, const float* __restrict__ dinv,
    ushort* __restrict__ outB, float* __restrict__ Psum, float* __restrict__ Psq)
{
    constexpr int KT = K / 32, CT = DOUT / 16;
    int tid = threadIdx.x;
    int lane = tid & 63, wid = tid >> 6;
    int r0 = blockIdx.x * 64 + wid * 16;
    int arow = r0 + (lane & 15);
    if (arow >= N_NODES) arow = N_NODES - 1;
    const ushort* aptr = A + (size_t)arow * K + (lane >> 4) * 8;

    f32x4 acc[CT];
#pragma unroll
    for (int ct = 0; ct < CT; ct++) acc[ct] = (f32x4){0.f, 0.f, 0.f, 0.f};

#pragma unroll
    for (int kt = 0; kt < KT; kt++) {
        bf16x8 af = *(const bf16x8*)(aptr + kt * 32);
        const ushort* wp = Wfrag + ((size_t)(kt * CT) * 64 + lane) * 8;
#pragma unroll
        for (int ct = 0; ct < CT; ct++) {
            bf16x8 bfr = *(const bf16x8*)(wp + (size_t)ct * 64 * 8);
            acc[ct] = __builtin_amdgcn_mfma_f32_16x16x32_bf16(af, bfr, acc[ct], 0, 0, 0);
        }
    }

    int colbase = lane & 15;
    int rgrp = lane >> 4;
    int rows[4]; bool rok[4];
    float rP[4], rD[4];
#pragma unroll
    for (int i = 0; i < 4; i++) {
        int r = r0 + rgrp * 4 + i;
        rows[i] = r;
        rok[i] = (r < N_NODES);
        int rc = rok[i] ? r : 0;
        if constexpr (MODE == 1) rP[i] = rowsumP[rc];
        else rD[i] = dinv[rc];
    }

    __shared__ float ssum[DOUT], ssq[DOUT];
    if constexpr (MODE <= 1) {
        for (int c = tid; c < DOUT; c += 256) { ssum[c] = 0.f; ssq[c] = 0.f; }
        __syncthreads();
    }

#pragma unroll
    for (int ct = 0; ct < CT; ct++) {
        int col = ct * 16 + colbase;
        float b = bias[col];
        float b2 = 0.f;
        if constexpr (MODE == 1) b2 = bias2[col];
        float cs = 0.f, cq = 0.f;
#pragma unroll
        for (int i = 0; i < 4; i++) {
            float v = acc[ct][i] + b;
            if constexpr (MODE == 1) v = fmaf(rP[i], b2, v);
            if constexpr (MODE <= 1) v = fmaxf(v, 0.f);
            float w = (MODE == 1) ? v : rD[i] * v;
            if (rok[i]) {
                outB[(size_t)rows[i] * DOUT + col] = f2bf(w);
                if constexpr (MODE <= 1) { cs += v; cq += v * v; }
            }
        }
        if constexpr (MODE <= 1) {
            cs += __shfl_xor(cs, 16); cs += __shfl_xor(cs, 32);
            cq += __shfl_xor(cq, 16); cq += __shfl_xor(cq, 32);
            if (rgrp == 0) {
                atomicAdd(&ssum[col], cs);
                atomicAdd(&ssq[col], cq);
            }
        }
    }
    if constexpr (MODE <= 1) {
        __syncthreads();
        for (int c = tid; c < DOUT; c += 256) {
            Psum[(size_t)c * gridDim.x + blockIdx.x] = ssum[c];
            Psq[(size_t)c * gridDim.x + blockIdx.x] = ssq[c];
        }
    }
}

// ---------------- BN stat reduce -> scale/shift ----------------
__global__ __launch_bounds__(256) void reduce_bn_kernel(
    const float* __restrict__ Psum, const float* __restrict__ Psq, int nb,
    const float* __restrict__ g, const float* __restrict__ be,
    float* __restrict__ sOut, float* __restrict__ uOut)
{
    int c = blockIdx.x, t = threadIdx.x;
    float s = 0.f, q = 0.f;
    for (int i = t; i < nb; i += 256) {
        s += Psum[(size_t)c * nb + i];
        q += Psq[(size_t)c * nb + i];
    }
    __shared__ float rs[256], rq[256];
    rs[t] = s; rq[t] = q;
    __syncthreads();
    for (int off = 128; off > 0; off >>= 1) {
        if (t < off) { rs[t] += rs[t + off]; rq[t] += rq[t + off]; }
        __syncthreads();
    }
    if (t == 0) {
        float mu = rs[0] * (1.0f / N_NODES);
        float var = rq[0] * (1.0f / N_NODES) - mu * mu;
        float sv = g[c] * rsqrtf(var + BN_EPS);
        sOut[c] = sv;
        uOut[c] = be[c] - mu * sv;
    }
}

// ---------------- fold: Wf = s (row) * W ; v[c] = u @ W[:,c] ----------------
__global__ void foldW_kernel(const float* __restrict__ W, const float* __restrict__ s,
                             const float* __restrict__ u, float* __restrict__ Wf,
                             float* __restrict__ v, int din, int dout)
{
    int c = blockIdx.x, t = threadIdx.x;
    float contrib = 0.f;
    if (t < din) {
        float w = W[t * dout + c];
        Wf[t * dout + c] = s[t] * w;
        contrib = u[t] * w;
    }
    __shared__ float red[128];
    red[t] = contrib;
    __syncthreads();
    for (int off = 64; off > 0; off >>= 1) {
        if (t < off) red[t] += red[t + off];
        __syncthreads();
    }
    if (t == 0) v[c] = red[0];
}

// ---------------- final: h4 = s4*t4+u4 (t4 [N,32] f32), logits = h4@Wc+bc ----------------
__global__ __launch_bounds__(256) void final_kernel(
    const float* __restrict__ t4, const float* __restrict__ sArr,
    const float* __restrict__ uArr, const float* __restrict__ Wc,
    const float* __restrict__ bc, float* __restrict__ out_logits,
    float* __restrict__ out_h)
{
    __shared__ float sc[32], sh2[32], Wcs[160], bcs[5];
    int t = threadIdx.x;
    if (t < 32) { sc[t] = sArr[t]; sh2[t] = uArr[t]; }
    if (t < 160) Wcs[t] = Wc[t];
    if (t < 5) bcs[t] = bc[t];
    __syncthreads();
    int i = blockIdx.x * blockDim.x + t;
    if (i >= N_NODES) return;
    float hv[32];
#pragma unroll
    for (int f0 = 0; f0 < 32; f0 += 4) {
        float4 v = *(const float4*)&t4[(size_t)i * 32 + f0];
        hv[f0 + 0] = fmaf(sc[f0 + 0], v.x, sh2[f0 + 0]);
        hv[f0 + 1] = fmaf(sc[f0 + 1], v.y, sh2[f0 + 1]);
        hv[f0 + 2] = fmaf(sc[f0 + 2], v.z, sh2[f0 + 2]);
        hv[f0 + 3] = fmaf(sc[f0 + 3], v.w, sh2[f0 + 3]);
    }
#pragma unroll
    for (int f0 = 0; f0 < 32; f0 += 4) {
        float4 v = {hv[f0], hv[f0 + 1], hv[f0 + 2], hv[f0 + 3]};
        *(float4*)&out_h[(size_t)i * 32 + f0] = v;
    }
    float o[5];
#pragma unroll
    for (int c = 0; c < 5; c++) o[c] = bcs[c];
#pragma unroll
    for (int f = 0; f < 32; f++) {
        float hvf = hv[f];
#pragma unroll
        for (int c = 0; c < 5; c++) o[c] = fmaf(hvf, Wcs[f * 5 + c], o[c]);
    }
#pragma unroll
    for (int c = 0; c < 5; c++) out_logits[(size_t)i * 5 + c] = o[c];
}

extern "C" void kernel_launch(void* const* d_in, const int* in_sizes, int n_in,
                              void* d_out, int out_size, void* d_ws, size_t ws_size,
                              hipStream_t stream)
{
    const float* x = (const float*)d_in[0];
    const int* ei = (const int*)d_in[1];
    const float* W1 = (const float*)d_in[2];
    const float* b1 = (const float*)d_in[3];
    const float* g1 = (const float*)d_in[4];
    const float* be1 = (const float*)d_in[5];
    const float* W2 = (const float*)d_in[6];
    const float* b2 = (const float*)d_in[7];
    const float* g2 = (const float*)d_in[8];
    const float* be2 = (const float*)d_in[9];
    const float* W3 = (const float*)d_in[10];
    const float* b3 = (const float*)d_in[11];
    const float* g3 = (const float*)d_in[12];
    const float* be3 = (const float*)d_in[13];
    const float* W4 = (const float*)d_in[14];
    const float* b4 = (const float*)d_in[15];
    const float* g4 = (const float*)d_in[16];
    const float* be4 = (const float*)d_in[17];
    const float* Wc = (const float*)d_in[18];
    const float* bc = (const float*)d_in[19];

    char* ws = (char*)d_ws;
    size_t off = 0;
    auto alloc = [&](size_t bytes) -> void* {
        void* p = ws + off;
        off += (bytes + 255) & ~(size_t)255;
        return p;
    };
    uint* ch = (uint*)alloc(65536 * 4);
    uint* bucketBase = (uint*)alloc(257 * 4);
    int2* pair = (int2*)alloc((size_t)N_EDGES * 8);
    int* rowptr = (int*)alloc((size_t)(N_NODES + 1) * 4);
    float* dinv = (float*)alloc((size_t)N_NODES * 4);
    int* colidx = (int*)alloc((size_t)N_EDGES * 4);
    int* flag = (int*)alloc(256);
    float* rowsumP = (float*)alloc((size_t)N_NODES * 4);
    uint* xs = (uint*)alloc((size_t)N_NODES * 32 * 4);   // [N,64] bf16, dinv-prescaled, padded
    float* Wf = (float*)alloc(128 * 128 * 4);
    ushort* Wfrag = (ushort*)alloc(32768);
    float* vB = (float*)alloc(128 * 4);
    float* sArr = (float*)alloc(128 * 4);
    float* uArr = (float*)alloc(128 * 4);
    float* Psum = (float*)alloc((size_t)128 * 2048 * 4);
    float* Psq = (float*)alloc((size_t)128 * 2048 * 4);
    ushort* P = (ushort*)alloc((size_t)N_NODES * 64 * 2); // a1 -> a2 -> z3s -> z4s
    ushort* Q = (ushort*)alloc((size_t)N_NODES * 64 * 2); // t1s -> t3
    ushort* R = (ushort*)alloc((size_t)N_NODES * 128 * 2); // t2 bf16; later t4 f32 [N,32]
    if (off > ws_size) return;

    // ---- CSR build ----
    detect_kernel<<<1, 256, 0, stream>>>(ei, flag);
    coarseA_kernel<<<NB_C, 256, 0, stream>>>(ei, flag, ch);
    scanB_kernel<<<1, 256, 0, stream>>>(ch, bucketBase);
    scatterC_kernel<<<NB_C, 256, 0, stream>>>(ei, flag, ch, pair);
    bucketD_kernel<<<NB_D, 256, 0, stream>>>(pair, bucketBase, rowptr, dinv, colidx);

    // ---- prep ----
    xscale_kernel<<<(N_NODES * 32 + 255) / 256, 256, 0, stream>>>(x, dinv, xs);
    packW_kernel<<<16, 256, 0, stream>>>(W1, Wfrag, 39, 64, 64);
    rowsum_kernel<<<512, 256, 0, stream>>>(rowptr, colidx, dinv, rowsumP);

    // ---- Layer 1: a1 = Ahat x ; t1 = relu(a1@W1+b1); stats1; t1s = bf16(dinv*t1) ----
    agg_kernel<64, 0><<<AGG_GRID, 256, 0, stream>>>(
        (const ushort*)xs, rowptr, colidx, dinv, nullptr, P, nullptr, nullptr, nullptr);
    mgemm_kernel<64, 64, 0><<<MG_GRID, 256, 0, stream>>>(
        P, Wfrag, b1, nullptr, nullptr, dinv, Q, Psum, Psq);
    reduce_bn_kernel<<<64, 256, 0, stream>>>(Psum, Psq, MG_GRID, g1, be1, sArr, uArr);
    foldW_kernel<<<128, 128, 0, stream>>>(W2, sArr, uArr, Wf, vB, 64, 128);
    packW_kernel<<<32, 256, 0, stream>>>(Wf, Wfrag, 64, 128, 64);

    // ---- Layer 2: a2 = Ahat t1s ; t2 = relu(a2@W2f + b2 + rowsumP*v2); stats2 ----
    agg_kernel<64, 0><<<AGG_GRID, 256, 0, stream>>>(
        Q, rowptr, colidx, dinv, nullptr, P, nullptr, nullptr, nullptr);
    mgemm_kernel<64, 128, 1><<<MG_GRID, 256, 0, stream>>>(
        P, Wfrag, b2, vB, rowsumP, nullptr, R, Psum, Psq);
    reduce_bn_kernel<<<128, 256, 0, stream>>>(Psum, Psq, MG_GRID, g2, be2, sArr, uArr);
    foldW_kernel<<<64, 128, 0, stream>>>(W3, sArr, uArr, Wf, vB, 128, 64);
    packW_kernel<<<32, 256, 0, stream>>>(Wf, Wfrag, 128, 64, 128);

    // ---- Layer 3: z3s = bf16(dinv*(t2@W3f+v3)); t3 = relu(Ahat z3 + b3); stats3 ----
    mgemm_kernel<128, 64, 2><<<MG_GRID, 256, 0, stream>>>(
        R, Wfrag, vB, nullptr, nullptr, dinv, P, nullptr, nullptr);
    agg_kernel<64, 1><<<AGG_GRID, 256, 0, stream>>>(
        P, rowptr, colidx, dinv, b3, Q, nullptr, Psum, Psq);
    reduce_bn_kernel<<<64, 256, 0, stream>>>(Psum, Psq, AGG_GRID, g3, be3, sArr, uArr);
    foldW_kernel<<<32, 128, 0, stream>>>(W4, sArr, uArr, Wf, vB, 64, 32);
    packW_kernel<<<16, 256, 0, stream>>>(Wf, Wfrag, 64, 32, 64);

    // ---- Layer 4: z4s = bf16(dinv*(t3@W4f+v4)); t4 = relu(Ahat z4 + b4); stats4 ----
    mgemm_kernel<64, 32, 2><<<MG_GRID, 256, 0, stream>>>(
        Q, Wfrag, vB, nullptr, nullptr, dinv, P, nullptr, nullptr);
    agg_kernel<32, 2><<<AGG_GRID, 256, 0, stream>>>(
        P, rowptr, colidx, dinv, b4, nullptr, (float*)R, Psum, Psq);
    reduce_bn_kernel<<<32, 256, 0, stream>>>(Psum, Psq, AGG_GRID, g4, be4, sArr, uArr);

    // ---- final ----
    float* out_logits = (float*)d_out;
    float* out_h = (float*)d_out + (size_t)N_NODES * 5;
    final_kernel<<<(N_NODES + 255) / 256, 256, 0, stream>>>((const float*)R, sArr, uArr,
                                                            Wc, bc, out_logits, out_h);
}